// Round 4
// baseline (419.959 us; speedup 1.0000x reference)
//
#include <hip/hip_runtime.h>

#define N_USERS 400000
#define N_ITEMS 200000
#define NNODES  600000   // N_USERS + N_ITEMS
#define D 64
#define B 8192
#define NBKT 8
#define BIN_CHUNK 2048

// ---------------------------------------------------------------------------
// bf16 helpers
// ---------------------------------------------------------------------------
__device__ __forceinline__ float bflo(unsigned u) { return __uint_as_float(u << 16); }
__device__ __forceinline__ float bfhi(unsigned u) { return __uint_as_float(u & 0xffff0000u); }
__device__ __forceinline__ unsigned f2bf(float f) {   // round-to-nearest-even
    unsigned u = __float_as_uint(f);
    unsigned r = u + 0x7fffu + ((u >> 16) & 1u);
    return r >> 16;
}

// acc[0..7] += v * bf16x8(word4)
__device__ __forceinline__ void unpack_fma(float* acc, uint4 wv, float v) {
    acc[0] += v * bflo(wv.x); acc[1] += v * bfhi(wv.x);
    acc[2] += v * bflo(wv.y); acc[3] += v * bfhi(wv.y);
    acc[4] += v * bflo(wv.z); acc[5] += v * bfhi(wv.z);
    acc[6] += v * bflo(wv.w); acc[7] += v * bfhi(wv.w);
}

// Bucket map balanced by expected edge count:
// users (avg deg 1.5): 4 buckets x 100K rows; items (avg deg 3): 4 x 50K rows.
__device__ __forceinline__ int bucket_of(int r) {
    return (r < N_USERS) ? (r / 100000) : (4 + (r - N_USERS) / 50000);
}

// ---------------------------------------------------------------------------
// scans
// ---------------------------------------------------------------------------
__global__ void k_scan1(int* __restrict__ deg, int* __restrict__ sums,
                        float* __restrict__ dinv, int n) {
    __shared__ int lds[256];
    int i = blockIdx.x * 256 + threadIdx.x;
    int v = (i < n) ? deg[i] : 0;
    if (i < n) dinv[i] = (v > 0) ? (float)(1.0 / sqrt((double)v)) : 0.0f;
    lds[threadIdx.x] = v;
    __syncthreads();
    for (int off = 1; off < 256; off <<= 1) {
        int t = (threadIdx.x >= off) ? lds[threadIdx.x - off] : 0;
        __syncthreads();
        lds[threadIdx.x] += t;
        __syncthreads();
    }
    int inc = lds[threadIdx.x];
    if (i < n) deg[i] = inc - v;
    if (threadIdx.x == 255) sums[blockIdx.x] = inc;
}

__global__ void k_scan2(int* __restrict__ sums, int n) {
    __shared__ int lds[1024];
    __shared__ int carry;
    if (threadIdx.x == 0) carry = 0;
    __syncthreads();
    for (int base = 0; base < n; base += 1024) {
        int i = base + threadIdx.x;
        int v = (i < n) ? sums[i] : 0;
        lds[threadIdx.x] = v;
        __syncthreads();
        for (int off = 1; off < 1024; off <<= 1) {
            int t = (threadIdx.x >= off) ? lds[threadIdx.x - off] : 0;
            __syncthreads();
            lds[threadIdx.x] += t;
            __syncthreads();
        }
        int inc = lds[threadIdx.x];
        if (i < n) sums[i] = (inc - v) + carry;
        __syncthreads();
        if (threadIdx.x == 1023) carry += lds[1023];
        __syncthreads();
    }
}

// scan3 + sample-flag seeding fused (extra blocks at the tail)
__global__ void k_scan3_flags(const int* __restrict__ deg, const int* __restrict__ sums,
                              int* __restrict__ row_ptr, int* __restrict__ nextp,
                              const int* __restrict__ users, const int* __restrict__ pos,
                              const int* __restrict__ neg,
                              char* __restrict__ flag1, char* __restrict__ flag2,
                              int nnz, int scan_blocks) {
    int bid = blockIdx.x;
    if (bid < scan_blocks) {
        int i = bid * blockDim.x + threadIdx.x;
        if (i >= NNODES) return;
        int rp = deg[i] + sums[i >> 8];
        row_ptr[i] = rp;
        nextp[i] = rp;
        if (i == 0) row_ptr[NNODES] = nnz;
    } else {
        int slot = (bid - scan_blocks) * blockDim.x + threadIdx.x;
        if (slot >= 3 * B) return;
        int set = slot / B;
        int b = slot - set * B;
        int r;
        if (set == 0)      r = users[b];
        else if (set == 1) r = N_USERS + pos[b];
        else               r = N_USERS + neg[b];
        flag2[r] = 1;
        flag1[r] = 1;
    }
}

// ---------------------------------------------------------------------------
// Phase A: ballot-based 8-way edge partition (NO LDS atomics - R3's 748K
// bank-conflict lesson) || mask popcount streaming.
// Per bin block (2048 edges): ballot-count -> 256-entry LDS scan -> 8 global
// atomics on 128B-padded counters -> ranked dense writes.
// ---------------------------------------------------------------------------
__global__ void k_binA(const int* __restrict__ rows, const int* __restrict__ cols,
                       int* __restrict__ bcount,
                       int* __restrict__ binned_r, int* __restrict__ binned_c,
                       const int* __restrict__ um, const int* __restrict__ im,
                       int* __restrict__ sizes, int nnz, int cap, int nbin, int S) {
    int bid = blockIdx.x;
    int t = threadIdx.x;
    bool is_bin = (bid % S == 0) && (bid / S < nbin);
    if (is_bin) {
        int chunk = bid / S;
        int e0 = chunk * BIN_CHUNK;
        int lane = t & 63;
        int wv = t >> 6;
        unsigned long long lt = (1ull << lane) - 1ull;   // lanes below me
        __shared__ int cnt[256];      // [bkt][iter][wave] = b*32 + k*4 + wv
        __shared__ int excl[257];
        __shared__ int gbase[NBKT];
        // pass 1: per-(wave,iter,bucket) counts via ballots
        #pragma unroll
        for (int k = 0; k < 8; ++k) {
            int e = e0 + k * 256 + t;
            int b = (e < nnz) ? bucket_of(rows[e]) : NBKT;
            unsigned long long b0 = __ballot(b & 1);
            unsigned long long b1 = __ballot(b & 2);
            unsigned long long b2 = __ballot(b & 4);
            unsigned long long vd = __ballot(b < NBKT);
            if (lane < NBKT) {
                int q = lane;
                unsigned long long m = ((q & 1) ? b0 : ~b0) & ((q & 2) ? b1 : ~b1)
                                     & ((q & 4) ? b2 : ~b2) & vd;
                cnt[q * 32 + k * 4 + wv] = (int)__popcll(m);
            }
        }
        __syncthreads();
        // pass 2: exclusive scan of the 256 counts (bucket-major order)
        int v = cnt[t];
        __shared__ int scn[256];
        scn[t] = v;
        __syncthreads();
        for (int off = 1; off < 256; off <<= 1) {
            int tv = (t >= off) ? scn[t - off] : 0;
            __syncthreads();
            scn[t] += tv;
            __syncthreads();
        }
        excl[t] = scn[t] - v;
        if (t == 255) excl[256] = scn[255];
        __syncthreads();
        if (t < NBKT) {
            int tot = excl[(t + 1) * 32] - excl[t * 32];
            gbase[t] = atomicAdd(&bcount[t * 32], tot);
        }
        __syncthreads();
        // pass 3: ranked placement
        #pragma unroll
        for (int k = 0; k < 8; ++k) {
            int e = e0 + k * 256 + t;
            int r = (e < nnz) ? rows[e] : 0;
            int b = (e < nnz) ? bucket_of(r) : NBKT;
            unsigned long long b0 = __ballot(b & 1);
            unsigned long long b1 = __ballot(b & 2);
            unsigned long long b2 = __ballot(b & 4);
            unsigned long long vd = __ballot(b < NBKT);
            if (b < NBKT) {
                unsigned long long m = ((b & 1) ? b0 : ~b0) & ((b & 2) ? b1 : ~b1)
                                     & ((b & 4) ? b2 : ~b2) & vd;
                int rank = (int)__popcll(m & lt);
                int off = excl[b * 32 + k * 4 + wv] - excl[b * 32];
                int pos = gbase[b] + off + rank;
                if (pos < cap) {
                    binned_r[(size_t)b * cap + pos] = r;
                    binned_c[(size_t)b * cap + pos] = cols[e];
                }
            }
        }
    } else {
        // sizes: 16 threads/row, int4 loads, shfl reduce
        int nbins_before = bid / S + 1;
        if (nbins_before > nbin) nbins_before = nbin;
        int sbid = bid - nbins_before;
        int gtid = sbid * 256 + t;
        int r = gtid >> 4;
        int q = gtid & 15;
        if (r >= NNODES) return;
        const int4* p = (const int4*)((r < N_USERS) ? um + (size_t)r * D
                                                    : im + (size_t)(r - N_USERS) * D);
        int4 v = p[q];
        int s = v.x + v.y + v.z + v.w;
        s += __shfl_xor(s, 1);
        s += __shfl_xor(s, 2);
        s += __shfl_xor(s, 4);
        s += __shfl_xor(s, 8);
        if (q == 0) sizes[r] = s;
    }
}

// ---------------------------------------------------------------------------
// Phase B1: deg histogram from binned edges. bucket = bid&7 -> each bucket's
// deg slice (<=400KB) stays in one XCD's L2 (round-robin block dispatch).
// ---------------------------------------------------------------------------
__global__ void k_b1(const int* __restrict__ binned_r, const int* __restrict__ bcount,
                     int* __restrict__ deg, int cap) {
    int b = blockIdx.x & 7;
    int n = bcount[b * 32];
    if (n > cap) n = cap;
    int idx = (blockIdx.x >> 3) * 256 + threadIdx.x;
    if (idx >= n) return;
    atomicAdd(&deg[binned_r[(size_t)b * cap + idx]], 1);
}

// ---------------------------------------------------------------------------
// Phase B2: XCD-local scatter (bucket = bid&7) + COO mark-pass1 tail blocks.
// pass1 race: monotone 0->1 flags, benign superset (see R2 note).
// ---------------------------------------------------------------------------
__global__ void k_b2(const int* __restrict__ binned_r, const int* __restrict__ binned_c,
                     const int* __restrict__ bcount,
                     int* __restrict__ nextp, int* __restrict__ pcol, int cap,
                     int nsc_blocks,
                     const int* __restrict__ rows, const int* __restrict__ cols,
                     char* __restrict__ flag2, int nnz) {
    int bid = blockIdx.x;
    if (bid < nsc_blocks) {
        int b = bid & 7;
        int n = bcount[b * 32];
        if (n > cap) n = cap;
        int idx = (bid >> 3) * 256 + threadIdx.x;
        if (idx >= n) return;
        size_t o = (size_t)b * cap + idx;
        int r = binned_r[o];
        int p = atomicAdd(&nextp[r], 1);
        pcol[p] = binned_c[o];
    } else {
        int e = (bid - nsc_blocks) * 256 + threadIdx.x;
        if (e >= nnz) return;
        if (flag2[rows[e]]) flag2[cols[e]] = 1;
    }
}

// ---------------------------------------------------------------------------
// COO mark pass2: flag1[col]=1 for edges with flag2[row]; plus flag1 |= flag2.
// ---------------------------------------------------------------------------
__global__ void k_pass2(const int* __restrict__ rows, const int* __restrict__ cols,
                        const char* __restrict__ flag2, char* __restrict__ flag1,
                        int nnz) {
    int t = blockIdx.x * blockDim.x + threadIdx.x;
    if (t < nnz) {
        if (flag2[rows[t]]) flag1[cols[t]] = 1;
    } else {
        int r = t - nnz;
        if (r < NNODES) {
            if (flag2[r]) flag1[r] = 1;
        }
    }
}

// ---------------------------------------------------------------------------
// Layer-1 SPMM from RAW f32 embeddings with inline prefix-mask (flag1 rows).
// ---------------------------------------------------------------------------
__global__ void k_spmm1(const int* __restrict__ row_ptr, const int* __restrict__ pcol,
                        const float* __restrict__ dinv, const int* __restrict__ sizes,
                        const char* __restrict__ flag1,
                        const float* __restrict__ ue, const float* __restrict__ ie,
                        unsigned* __restrict__ y1) {
    int tid = blockIdx.x * blockDim.x + threadIdx.x;
    int r = tid >> 3;
    if (r >= NNODES) return;
    if (!flag1[r]) return;
    int c8 = (tid & 7) << 3;          // f32 col base
    int s = row_ptr[r];
    int e = row_ptr[r + 1];
    float dr = dinv[r];
    float acc[8] = {0.f, 0.f, 0.f, 0.f, 0.f, 0.f, 0.f, 0.f};
    for (int i = s; i < e; ++i) {
        int c = pcol[i];
        float v = dr * dinv[c];
        int sz = sizes[c];
        const float* p = ((c < N_USERS) ? ue + (size_t)c * D
                                        : ie + (size_t)(c - N_USERS) * D) + c8;
        float4 e0 = *(const float4*)p;
        float4 e1 = *(const float4*)(p + 4);
        acc[0] += v * ((c8 + 0 < sz) ? e0.x : 0.f);
        acc[1] += v * ((c8 + 1 < sz) ? e0.y : 0.f);
        acc[2] += v * ((c8 + 2 < sz) ? e0.z : 0.f);
        acc[3] += v * ((c8 + 3 < sz) ? e0.w : 0.f);
        acc[4] += v * ((c8 + 4 < sz) ? e1.x : 0.f);
        acc[5] += v * ((c8 + 5 < sz) ? e1.y : 0.f);
        acc[6] += v * ((c8 + 6 < sz) ? e1.z : 0.f);
        acc[7] += v * ((c8 + 7 < sz) ? e1.w : 0.f);
    }
    uint4 o;
    o.x = f2bf(acc[0]) | (f2bf(acc[1]) << 16);
    o.y = f2bf(acc[2]) | (f2bf(acc[3]) << 16);
    o.z = f2bf(acc[4]) | (f2bf(acc[5]) << 16);
    o.w = f2bf(acc[6]) | (f2bf(acc[7]) << 16);
    *(uint4*)(y1 + (size_t)r * 32 + (tid & 7) * 4) = o;
}

// ---------------------------------------------------------------------------
// Layer-2 bf16 SPMM, flag2 rows only: x2[r] = sum val * y1[col].
// ---------------------------------------------------------------------------
__global__ void k_spmm2(const int* __restrict__ row_ptr, const int* __restrict__ pcol,
                        const float* __restrict__ dinv, const char* __restrict__ flag2,
                        const unsigned* __restrict__ y1, unsigned* __restrict__ x2) {
    int tid = blockIdx.x * blockDim.x + threadIdx.x;
    int r = tid >> 3;
    if (r >= NNODES) return;
    if (!flag2[r]) return;
    int cp = (tid & 7) << 2;
    int s = row_ptr[r];
    int e = row_ptr[r + 1];
    float dr = dinv[r];
    float acc[8] = {0.f, 0.f, 0.f, 0.f, 0.f, 0.f, 0.f, 0.f};
    int i = s;
    for (; i + 1 < e; i += 2) {
        int c0 = pcol[i], c1 = pcol[i + 1];
        float v0 = dr * dinv[c0], v1 = dr * dinv[c1];
        uint4 w0 = *(const uint4*)(y1 + (size_t)c0 * 32 + cp);
        uint4 w1 = *(const uint4*)(y1 + (size_t)c1 * 32 + cp);
        unpack_fma(acc, w0, v0);
        unpack_fma(acc, w1, v1);
    }
    if (i < e) {
        int c0 = pcol[i];
        float v0 = dr * dinv[c0];
        uint4 w0 = *(const uint4*)(y1 + (size_t)c0 * 32 + cp);
        unpack_fma(acc, w0, v0);
    }
    uint4 o;
    o.x = f2bf(acc[0]) | (f2bf(acc[1]) << 16);
    o.y = f2bf(acc[2]) | (f2bf(acc[3]) << 16);
    o.z = f2bf(acc[4]) | (f2bf(acc[5]) << 16);
    o.w = f2bf(acc[6]) | (f2bf(acc[7]) << 16);
    *(uint4*)(x2 + (size_t)r * 32 + cp) = o;
}

// ---------------------------------------------------------------------------
// Final sampled layer, fused epilogue + ego.
// ---------------------------------------------------------------------------
__global__ void k_spmm3(const int* __restrict__ row_ptr, const int* __restrict__ pcol,
                        const float* __restrict__ dinv, const int* __restrict__ sizes,
                        const float* __restrict__ ue, const float* __restrict__ ie,
                        const unsigned* __restrict__ y1, const unsigned* __restrict__ x2,
                        const int* __restrict__ users, const int* __restrict__ pos,
                        const int* __restrict__ neg, float* __restrict__ out) {
    int tid = blockIdx.x * blockDim.x + threadIdx.x;
    int slot = tid >> 3;
    if (slot >= 3 * B) return;
    int cp = (tid & 7) << 2;          // uint base
    int c8 = (tid & 7) << 3;          // f32 col base
    int set = slot / B;
    int b = slot - set * B;
    int r;
    if (set == 0)      r = users[b];
    else if (set == 1) r = N_USERS + pos[b];
    else               r = N_USERS + neg[b];
    int s = row_ptr[r];
    int e = row_ptr[r + 1];
    float dr = dinv[r];
    float acc[8] = {0.f, 0.f, 0.f, 0.f, 0.f, 0.f, 0.f, 0.f};
    uint4 g1 = *(const uint4*)(y1 + (size_t)r * 32 + cp);
    uint4 g2 = *(const uint4*)(x2 + (size_t)r * 32 + cp);
    unpack_fma(acc, g1, 1.0f);
    unpack_fma(acc, g2, 1.0f);
    int i = s;
    for (; i + 1 < e; i += 2) {
        int c0 = pcol[i], c1 = pcol[i + 1];
        float v0 = dr * dinv[c0], v1 = dr * dinv[c1];
        uint4 w0 = *(const uint4*)(x2 + (size_t)c0 * 32 + cp);
        uint4 w1 = *(const uint4*)(x2 + (size_t)c1 * 32 + cp);
        unpack_fma(acc, w0, v0);
        unpack_fma(acc, w1, v1);
    }
    if (i < e) {
        int c0 = pcol[i];
        float v0 = dr * dinv[c0];
        uint4 w0 = *(const uint4*)(x2 + (size_t)c0 * 32 + cp);
        unpack_fma(acc, w0, v0);
    }
    const float* p = ((r < N_USERS) ? ue + (size_t)r * D
                                    : ie + (size_t)(r - N_USERS) * D) + c8;
    float4 e0 = *(const float4*)p;
    float4 e1 = *(const float4*)(p + 4);
    int sz = sizes[r];
    e0.x = (c8 + 0 < sz) ? e0.x : 0.f; e0.y = (c8 + 1 < sz) ? e0.y : 0.f;
    e0.z = (c8 + 2 < sz) ? e0.z : 0.f; e0.w = (c8 + 3 < sz) ? e0.w : 0.f;
    e1.x = (c8 + 4 < sz) ? e1.x : 0.f; e1.y = (c8 + 5 < sz) ? e1.y : 0.f;
    e1.z = (c8 + 6 < sz) ? e1.z : 0.f; e1.w = (c8 + 7 < sz) ? e1.w : 0.f;
    float4 oa, ob;
    oa.x = (e0.x + acc[0]) * 0.25f; oa.y = (e0.y + acc[1]) * 0.25f;
    oa.z = (e0.z + acc[2]) * 0.25f; oa.w = (e0.w + acc[3]) * 0.25f;
    ob.x = (e1.x + acc[4]) * 0.25f; ob.y = (e1.y + acc[5]) * 0.25f;
    ob.z = (e1.z + acc[6]) * 0.25f; ob.w = (e1.w + acc[7]) * 0.25f;
    float* o0 = out + (size_t)slot * D + c8;
    float* o1 = out + (size_t)(3 * B + slot) * D + c8;
    *(float4*)o0 = oa; *(float4*)(o0 + 4) = ob;
    *(float4*)o1 = e0; *(float4*)(o1 + 4) = e1;
}

extern "C" void kernel_launch(void* const* d_in, const int* in_sizes, int n_in,
                              void* d_out, int out_size, void* d_ws, size_t ws_size,
                              hipStream_t stream) {
    const float* ue   = (const float*)d_in[0];
    const float* ie   = (const float*)d_in[1];
    const int*   um   = (const int*)d_in[2];
    const int*   im   = (const int*)d_in[3];
    const int*   rows = (const int*)d_in[4];
    const int*   cols = (const int*)d_in[5];
    const int*   users = (const int*)d_in[7];
    const int*   pos   = (const int*)d_in[8];
    const int*   neg   = (const int*)d_in[9];
    int nnz = in_sizes[4];

    float* out = (float*)d_out;

    // workspace layout (16B-aligned bf16 node buffers first)
    unsigned short* Y1 = (unsigned short*)d_ws;         // NNODES*D bf16
    unsigned short* X2 = Y1 + (size_t)NNODES * D;       // NNODES*D bf16
    int*   deg     = (int*)(X2 + (size_t)NNODES * D);   // NNODES
    int*   row_ptr = deg + NNODES;                      // NNODES+1
    int*   nextp   = row_ptr + NNODES + 1;              // NNODES
    int*   sizes   = nextp + NNODES;                    // NNODES
    int*   sums    = sizes + NNODES;                    // up to 4096
    int*   bcount  = sums + 4096;                       // 8 counters, 128B-padded
    float* dinv    = (float*)(bcount + 256);            // NNODES
    int*   pcol    = (int*)(dinv + NNODES);             // nnz
    char*  flag1   = (char*)(pcol + nnz);               // NNODES
    char*  flag2   = flag1 + NNODES;                    // NNODES
    int cap = nnz / NBKT + 16384;                       // 45-sigma bucket margin
    int* binned_r = (int*)(((uintptr_t)(flag2 + NNODES) + 15) & ~(uintptr_t)15);
    int* binned_c = binned_r + (size_t)NBKT * cap;

    const int blk = 256;
    const int scan_blocks = (NNODES + 255) / 256;       // 2344
    const int flag_blocks = (3 * B + blk - 1) / blk;    // 96

    hipMemsetAsync(deg, 0, (size_t)NNODES * sizeof(int), stream);
    hipMemsetAsync(bcount, 0, 256 * sizeof(int), stream);
    hipMemsetAsync(flag1, 0, (size_t)2 * NNODES, stream);

    // --- Phase A: ballot-partition edges || mask popcount streaming ---
    {
        int nbin = (nnz + BIN_CHUNK - 1) / BIN_CHUNK;   // ~586
        int nsz  = (NNODES * 16 + blk - 1) / blk;       // 37500
        int grid = nbin + nsz;
        int S = grid / nbin;                            // interleave stride (~65)
        k_binA<<<grid, blk, 0, stream>>>(rows, cols, bcount, binned_r, binned_c,
                                         um, im, sizes, nnz, cap, nbin, S);
    }

    int bpb = (cap + 255) / 256;                        // blocks per bucket
    int nsc_blocks = NBKT * bpb;

    // --- Phase B1: deg histogram (XCD-local atomics) ---
    k_b1<<<nsc_blocks, blk, 0, stream>>>(binned_r, bcount, deg, cap);

    // --- scans + sample-flag seeding ---
    k_scan1<<<scan_blocks, 256, 0, stream>>>(deg, sums, dinv, NNODES);
    k_scan2<<<1, 1024, 0, stream>>>(sums, scan_blocks);
    k_scan3_flags<<<scan_blocks + flag_blocks, blk, 0, stream>>>(
        deg, sums, row_ptr, nextp, users, pos, neg, flag1, flag2, nnz, scan_blocks);

    // --- Phase B2: XCD-local scatter || COO mark-pass1 ---
    {
        int p1_blocks = (nnz + blk - 1) / blk;
        k_b2<<<nsc_blocks + p1_blocks, blk, 0, stream>>>(binned_r, binned_c, bcount,
                                                         nextp, pcol, cap, nsc_blocks,
                                                         rows, cols, flag2, nnz);
    }

    // --- mark pass2: flag1 = flag2 U nbrs(flag2) ---
    k_pass2<<<(nnz + NNODES + blk - 1) / blk, blk, 0, stream>>>(rows, cols, flag2, flag1, nnz);

    int n_full = NNODES * 8;
    int n_samp = 3 * B * 8;

    k_spmm1<<<(n_full + blk - 1) / blk, blk, 0, stream>>>(row_ptr, pcol, dinv, sizes, flag1,
                                                          ue, ie, (unsigned*)Y1);
    k_spmm2<<<(n_full + blk - 1) / blk, blk, 0, stream>>>(row_ptr, pcol, dinv, flag2,
                                                          (const unsigned*)Y1, (unsigned*)X2);
    k_spmm3<<<(n_samp + blk - 1) / blk, blk, 0, stream>>>(row_ptr, pcol, dinv, sizes,
                                                          ue, ie,
                                                          (const unsigned*)Y1,
                                                          (const unsigned*)X2,
                                                          users, pos, neg, out);
}

// Round 5
// 255.639 us; speedup vs baseline: 1.6428x; 1.6428x over previous
//
#include <hip/hip_runtime.h>

#define N_USERS 400000
#define N_ITEMS 200000
#define NNODES  600000   // N_USERS + N_ITEMS
#define D 64
#define B 8192
#define NBKT 8

// ---------------------------------------------------------------------------
// bf16 helpers
// ---------------------------------------------------------------------------
__device__ __forceinline__ float bflo(unsigned u) { return __uint_as_float(u << 16); }
__device__ __forceinline__ float bfhi(unsigned u) { return __uint_as_float(u & 0xffff0000u); }
__device__ __forceinline__ unsigned f2bf(float f) {   // round-to-nearest-even
    unsigned u = __float_as_uint(f);
    unsigned r = u + 0x7fffu + ((u >> 16) & 1u);
    return r >> 16;
}

// acc[0..7] += v * bf16x8(word4)
__device__ __forceinline__ void unpack_fma(float* acc, uint4 wv, float v) {
    acc[0] += v * bflo(wv.x); acc[1] += v * bfhi(wv.x);
    acc[2] += v * bflo(wv.y); acc[3] += v * bfhi(wv.y);
    acc[4] += v * bflo(wv.z); acc[5] += v * bfhi(wv.z);
    acc[6] += v * bflo(wv.w); acc[7] += v * bfhi(wv.w);
}

// Bucket map balanced by expected edge count:
// users (avg deg 1.5): 4 buckets x 100K rows; items (avg deg 3): 4 x 50K rows.
__device__ __forceinline__ int bucket_of(int r) {
    return (r < N_USERS) ? (r / 100000) : (4 + (r - N_USERS) / 50000);
}

// ---------------------------------------------------------------------------
// scans
// ---------------------------------------------------------------------------
__global__ void k_scan1(int* __restrict__ deg, int* __restrict__ sums,
                        float* __restrict__ dinv, int n) {
    __shared__ int lds[256];
    int i = blockIdx.x * 256 + threadIdx.x;
    int v = (i < n) ? deg[i] : 0;
    if (i < n) dinv[i] = (v > 0) ? (float)(1.0 / sqrt((double)v)) : 0.0f;
    lds[threadIdx.x] = v;
    __syncthreads();
    for (int off = 1; off < 256; off <<= 1) {
        int t = (threadIdx.x >= off) ? lds[threadIdx.x - off] : 0;
        __syncthreads();
        lds[threadIdx.x] += t;
        __syncthreads();
    }
    int inc = lds[threadIdx.x];
    if (i < n) deg[i] = inc - v;
    if (threadIdx.x == 255) sums[blockIdx.x] = inc;
}

__global__ void k_scan2(int* __restrict__ sums, int n) {
    __shared__ int lds[1024];
    __shared__ int carry;
    if (threadIdx.x == 0) carry = 0;
    __syncthreads();
    for (int base = 0; base < n; base += 1024) {
        int i = base + threadIdx.x;
        int v = (i < n) ? sums[i] : 0;
        lds[threadIdx.x] = v;
        __syncthreads();
        for (int off = 1; off < 1024; off <<= 1) {
            int t = (threadIdx.x >= off) ? lds[threadIdx.x - off] : 0;
            __syncthreads();
            lds[threadIdx.x] += t;
            __syncthreads();
        }
        int inc = lds[threadIdx.x];
        if (i < n) sums[i] = (inc - v) + carry;
        __syncthreads();
        if (threadIdx.x == 1023) carry += lds[1023];
        __syncthreads();
    }
}

__global__ void k_scan3(const int* __restrict__ deg, const int* __restrict__ sums,
                        int* __restrict__ row_ptr, int* __restrict__ nextp, int nnz) {
    int i = blockIdx.x * blockDim.x + threadIdx.x;
    if (i >= NNODES) return;
    int rp = deg[i] + sums[i >> 8];
    row_ptr[i] = rp;
    nextp[i] = rp;
    if (i == 0) row_ptr[NNODES] = nnz;
}

// ---------------------------------------------------------------------------
// FAT1: XCD-filtered deg histogram || mask-popcount streaming || sample seed.
// Group structure: bid = (group << 3) | x, x = bid&7 -> XCD (round-robin
// dispatch). group = st*17 + slot:
//   slot 0..7 : histX  — chunk st*8+slot; the 8 x-blocks of the group each
//               commit only rows with bucket_of(r)==x  -> deg atomics stay
//               in XCD-local L2 (rows[] chunk is L3-hit after first reader).
//   slot 8..15: sizes  — 16 threads/row, int4 loads, shfl reduce.
//   slot 16   : seed   — flag1/flag2 = 1 for the 3B sampled rows.
// No LDS, no syncthreads, light blocks (R3/R4 lesson: few fat blocks with
// LDS scans straggle; many light blocks don't).
// ---------------------------------------------------------------------------
__global__ void k_fat1(const int* __restrict__ rows,
                       const int* __restrict__ um, const int* __restrict__ im,
                       int* __restrict__ sizes, int* __restrict__ deg,
                       const int* __restrict__ users, const int* __restrict__ pos,
                       const int* __restrict__ neg,
                       char* __restrict__ flag1, char* __restrict__ flag2, int nnz) {
    int bid = blockIdx.x;
    int x = bid & 7;
    int g = bid >> 3;
    int st = g / 17;
    int slot = g - st * 17;
    int t = threadIdx.x;
    if (slot < 8) {
        int e = (st * 8 + slot) * 256 + t;
        if (e >= nnz) return;
        int r = rows[e];
        if (bucket_of(r) == x) atomicAdd(&deg[r], 1);
    } else if (slot < 16) {
        int sb = (st * 8 + (slot - 8)) * 8 + x;
        int gtid = sb * 256 + t;
        int r = gtid >> 4;
        int q = gtid & 15;
        if (r >= NNODES) return;
        const int4* p = (const int4*)((r < N_USERS) ? um + (size_t)r * D
                                                    : im + (size_t)(r - N_USERS) * D);
        int4 v = p[q];
        int s = v.x + v.y + v.z + v.w;
        s += __shfl_xor(s, 1);
        s += __shfl_xor(s, 2);
        s += __shfl_xor(s, 4);
        s += __shfl_xor(s, 8);
        if (q == 0) sizes[r] = s;
    } else {
        int slot2 = (st * 8 + x) * 256 + t;
        if (slot2 >= 3 * B) return;
        int set = slot2 / B;
        int b = slot2 - set * B;
        int r;
        if (set == 0)      r = users[b];
        else if (set == 1) r = N_USERS + pos[b];
        else               r = N_USERS + neg[b];
        flag2[r] = 1;
        flag1[r] = 1;
    }
}

// ---------------------------------------------------------------------------
// FAT2: XCD-filtered scatter || COO mark-pass1.
// group = st*9 + slot; slot 0..7: scatterX chunk st*8+slot, filter bucket x
// (nextp atomics + pcol writes stay in XCD-local L2 windows -> kills the
// 19x write amplification R2 measured). slot 8: pass1 chunk st*8+x.
// pass1 race: monotone 0->1 flags, benign superset (R2 note).
// ---------------------------------------------------------------------------
__global__ void k_fat2(const int* __restrict__ rows, const int* __restrict__ cols,
                       int* __restrict__ nextp, int* __restrict__ pcol,
                       char* __restrict__ flag2, int nnz) {
    int bid = blockIdx.x;
    int x = bid & 7;
    int g = bid >> 3;
    int st = g / 9;
    int slot = g - st * 9;
    int t = threadIdx.x;
    if (slot < 8) {
        int e = (st * 8 + slot) * 256 + t;
        if (e >= nnz) return;
        int r = rows[e];
        if (bucket_of(r) != x) return;
        int p = atomicAdd(&nextp[r], 1);
        pcol[p] = cols[e];
    } else {
        int e = (st * 8 + x) * 256 + t;
        if (e >= nnz) return;
        if (flag2[rows[e]]) flag2[cols[e]] = 1;
    }
}

// ---------------------------------------------------------------------------
// COO mark pass2: flag1[col]=1 for edges with flag2[row]; plus flag1 |= flag2.
// ---------------------------------------------------------------------------
__global__ void k_pass2(const int* __restrict__ rows, const int* __restrict__ cols,
                        const char* __restrict__ flag2, char* __restrict__ flag1,
                        int nnz) {
    int t = blockIdx.x * blockDim.x + threadIdx.x;
    if (t < nnz) {
        if (flag2[rows[t]]) flag1[cols[t]] = 1;
    } else {
        int r = t - nnz;
        if (r < NNODES) {
            if (flag2[r]) flag1[r] = 1;
        }
    }
}

// ---------------------------------------------------------------------------
// Layer-1 SPMM from RAW f32 embeddings with inline prefix-mask (flag1 rows).
// ---------------------------------------------------------------------------
__global__ void k_spmm1(const int* __restrict__ row_ptr, const int* __restrict__ pcol,
                        const float* __restrict__ dinv, const int* __restrict__ sizes,
                        const char* __restrict__ flag1,
                        const float* __restrict__ ue, const float* __restrict__ ie,
                        unsigned* __restrict__ y1) {
    int tid = blockIdx.x * blockDim.x + threadIdx.x;
    int r = tid >> 3;
    if (r >= NNODES) return;
    if (!flag1[r]) return;
    int c8 = (tid & 7) << 3;          // f32 col base
    int s = row_ptr[r];
    int e = row_ptr[r + 1];
    float dr = dinv[r];
    float acc[8] = {0.f, 0.f, 0.f, 0.f, 0.f, 0.f, 0.f, 0.f};
    for (int i = s; i < e; ++i) {
        int c = pcol[i];
        float v = dr * dinv[c];
        int sz = sizes[c];
        const float* p = ((c < N_USERS) ? ue + (size_t)c * D
                                        : ie + (size_t)(c - N_USERS) * D) + c8;
        float4 e0 = *(const float4*)p;
        float4 e1 = *(const float4*)(p + 4);
        acc[0] += v * ((c8 + 0 < sz) ? e0.x : 0.f);
        acc[1] += v * ((c8 + 1 < sz) ? e0.y : 0.f);
        acc[2] += v * ((c8 + 2 < sz) ? e0.z : 0.f);
        acc[3] += v * ((c8 + 3 < sz) ? e0.w : 0.f);
        acc[4] += v * ((c8 + 4 < sz) ? e1.x : 0.f);
        acc[5] += v * ((c8 + 5 < sz) ? e1.y : 0.f);
        acc[6] += v * ((c8 + 6 < sz) ? e1.z : 0.f);
        acc[7] += v * ((c8 + 7 < sz) ? e1.w : 0.f);
    }
    uint4 o;
    o.x = f2bf(acc[0]) | (f2bf(acc[1]) << 16);
    o.y = f2bf(acc[2]) | (f2bf(acc[3]) << 16);
    o.z = f2bf(acc[4]) | (f2bf(acc[5]) << 16);
    o.w = f2bf(acc[6]) | (f2bf(acc[7]) << 16);
    *(uint4*)(y1 + (size_t)r * 32 + (tid & 7) * 4) = o;
}

// ---------------------------------------------------------------------------
// Layer-2 bf16 SPMM, flag2 rows only: x2[r] = sum val * y1[col].
// ---------------------------------------------------------------------------
__global__ void k_spmm2(const int* __restrict__ row_ptr, const int* __restrict__ pcol,
                        const float* __restrict__ dinv, const char* __restrict__ flag2,
                        const unsigned* __restrict__ y1, unsigned* __restrict__ x2) {
    int tid = blockIdx.x * blockDim.x + threadIdx.x;
    int r = tid >> 3;
    if (r >= NNODES) return;
    if (!flag2[r]) return;
    int cp = (tid & 7) << 2;
    int s = row_ptr[r];
    int e = row_ptr[r + 1];
    float dr = dinv[r];
    float acc[8] = {0.f, 0.f, 0.f, 0.f, 0.f, 0.f, 0.f, 0.f};
    int i = s;
    for (; i + 1 < e; i += 2) {
        int c0 = pcol[i], c1 = pcol[i + 1];
        float v0 = dr * dinv[c0], v1 = dr * dinv[c1];
        uint4 w0 = *(const uint4*)(y1 + (size_t)c0 * 32 + cp);
        uint4 w1 = *(const uint4*)(y1 + (size_t)c1 * 32 + cp);
        unpack_fma(acc, w0, v0);
        unpack_fma(acc, w1, v1);
    }
    if (i < e) {
        int c0 = pcol[i];
        float v0 = dr * dinv[c0];
        uint4 w0 = *(const uint4*)(y1 + (size_t)c0 * 32 + cp);
        unpack_fma(acc, w0, v0);
    }
    uint4 o;
    o.x = f2bf(acc[0]) | (f2bf(acc[1]) << 16);
    o.y = f2bf(acc[2]) | (f2bf(acc[3]) << 16);
    o.z = f2bf(acc[4]) | (f2bf(acc[5]) << 16);
    o.w = f2bf(acc[6]) | (f2bf(acc[7]) << 16);
    *(uint4*)(x2 + (size_t)r * 32 + cp) = o;
}

// ---------------------------------------------------------------------------
// Final sampled layer, fused epilogue + ego.
// ---------------------------------------------------------------------------
__global__ void k_spmm3(const int* __restrict__ row_ptr, const int* __restrict__ pcol,
                        const float* __restrict__ dinv, const int* __restrict__ sizes,
                        const float* __restrict__ ue, const float* __restrict__ ie,
                        const unsigned* __restrict__ y1, const unsigned* __restrict__ x2,
                        const int* __restrict__ users, const int* __restrict__ pos,
                        const int* __restrict__ neg, float* __restrict__ out) {
    int tid = blockIdx.x * blockDim.x + threadIdx.x;
    int slot = tid >> 3;
    if (slot >= 3 * B) return;
    int cp = (tid & 7) << 2;          // uint base
    int c8 = (tid & 7) << 3;          // f32 col base
    int set = slot / B;
    int b = slot - set * B;
    int r;
    if (set == 0)      r = users[b];
    else if (set == 1) r = N_USERS + pos[b];
    else               r = N_USERS + neg[b];
    int s = row_ptr[r];
    int e = row_ptr[r + 1];
    float dr = dinv[r];
    float acc[8] = {0.f, 0.f, 0.f, 0.f, 0.f, 0.f, 0.f, 0.f};
    uint4 g1 = *(const uint4*)(y1 + (size_t)r * 32 + cp);
    uint4 g2 = *(const uint4*)(x2 + (size_t)r * 32 + cp);
    unpack_fma(acc, g1, 1.0f);
    unpack_fma(acc, g2, 1.0f);
    int i = s;
    for (; i + 1 < e; i += 2) {
        int c0 = pcol[i], c1 = pcol[i + 1];
        float v0 = dr * dinv[c0], v1 = dr * dinv[c1];
        uint4 w0 = *(const uint4*)(x2 + (size_t)c0 * 32 + cp);
        uint4 w1 = *(const uint4*)(x2 + (size_t)c1 * 32 + cp);
        unpack_fma(acc, w0, v0);
        unpack_fma(acc, w1, v1);
    }
    if (i < e) {
        int c0 = pcol[i];
        float v0 = dr * dinv[c0];
        uint4 w0 = *(const uint4*)(x2 + (size_t)c0 * 32 + cp);
        unpack_fma(acc, w0, v0);
    }
    const float* p = ((r < N_USERS) ? ue + (size_t)r * D
                                    : ie + (size_t)(r - N_USERS) * D) + c8;
    float4 e0 = *(const float4*)p;
    float4 e1 = *(const float4*)(p + 4);
    int sz = sizes[r];
    e0.x = (c8 + 0 < sz) ? e0.x : 0.f; e0.y = (c8 + 1 < sz) ? e0.y : 0.f;
    e0.z = (c8 + 2 < sz) ? e0.z : 0.f; e0.w = (c8 + 3 < sz) ? e0.w : 0.f;
    e1.x = (c8 + 4 < sz) ? e1.x : 0.f; e1.y = (c8 + 5 < sz) ? e1.y : 0.f;
    e1.z = (c8 + 6 < sz) ? e1.z : 0.f; e1.w = (c8 + 7 < sz) ? e1.w : 0.f;
    float4 oa, ob;
    oa.x = (e0.x + acc[0]) * 0.25f; oa.y = (e0.y + acc[1]) * 0.25f;
    oa.z = (e0.z + acc[2]) * 0.25f; oa.w = (e0.w + acc[3]) * 0.25f;
    ob.x = (e1.x + acc[4]) * 0.25f; ob.y = (e1.y + acc[5]) * 0.25f;
    ob.z = (e1.z + acc[6]) * 0.25f; ob.w = (e1.w + acc[7]) * 0.25f;
    float* o0 = out + (size_t)slot * D + c8;
    float* o1 = out + (size_t)(3 * B + slot) * D + c8;
    *(float4*)o0 = oa; *(float4*)(o0 + 4) = ob;
    *(float4*)o1 = e0; *(float4*)(o1 + 4) = e1;
}

extern "C" void kernel_launch(void* const* d_in, const int* in_sizes, int n_in,
                              void* d_out, int out_size, void* d_ws, size_t ws_size,
                              hipStream_t stream) {
    const float* ue   = (const float*)d_in[0];
    const float* ie   = (const float*)d_in[1];
    const int*   um   = (const int*)d_in[2];
    const int*   im   = (const int*)d_in[3];
    const int*   rows = (const int*)d_in[4];
    const int*   cols = (const int*)d_in[5];
    const int*   users = (const int*)d_in[7];
    const int*   pos   = (const int*)d_in[8];
    const int*   neg   = (const int*)d_in[9];
    int nnz = in_sizes[4];

    float* out = (float*)d_out;

    // workspace layout (16B-aligned bf16 node buffers first)
    unsigned short* Y1 = (unsigned short*)d_ws;         // NNODES*D bf16
    unsigned short* X2 = Y1 + (size_t)NNODES * D;       // NNODES*D bf16
    int*   deg     = (int*)(X2 + (size_t)NNODES * D);   // NNODES
    int*   row_ptr = deg + NNODES;                      // NNODES+1
    int*   nextp   = row_ptr + NNODES + 1;              // NNODES
    int*   sizes   = nextp + NNODES;                    // NNODES
    int*   sums    = sizes + NNODES;                    // up to 4096
    float* dinv    = (float*)(sums + 4096);             // NNODES
    int*   pcol    = (int*)(dinv + NNODES);             // nnz
    char*  flag1   = (char*)(pcol + nnz);               // NNODES
    char*  flag2   = flag1 + NNODES;                    // NNODES

    const int blk = 256;
    const int scan_blocks = (NNODES + 255) / 256;       // 2344
    int chunks = (nnz + 255) / 256;                     // 4688
    int nst = (chunks + 7) / 8;                         // 586 supertiles
    // sizes coverage check: nst*8 groups * 8 = 37504 >= 37500 needed

    hipMemsetAsync(deg, 0, (size_t)NNODES * sizeof(int), stream);
    hipMemsetAsync(flag1, 0, (size_t)2 * NNODES, stream);

    // --- FAT1: histX || sizes || seed ---
    k_fat1<<<nst * 17 * 8, blk, 0, stream>>>(rows, um, im, sizes, deg,
                                             users, pos, neg, flag1, flag2, nnz);

    // --- scans ---
    k_scan1<<<scan_blocks, 256, 0, stream>>>(deg, sums, dinv, NNODES);
    k_scan2<<<1, 1024, 0, stream>>>(sums, scan_blocks);
    k_scan3<<<(NNODES + blk - 1) / blk, blk, 0, stream>>>(deg, sums, row_ptr, nextp, nnz);

    // --- FAT2: scatterX || mark-pass1 ---
    k_fat2<<<nst * 9 * 8, blk, 0, stream>>>(rows, cols, nextp, pcol, flag2, nnz);

    // --- mark pass2: flag1 = flag2 U nbrs(flag2) ---
    k_pass2<<<(nnz + NNODES + blk - 1) / blk, blk, 0, stream>>>(rows, cols, flag2, flag1, nnz);

    int n_full = NNODES * 8;
    int n_samp = 3 * B * 8;

    k_spmm1<<<(n_full + blk - 1) / blk, blk, 0, stream>>>(row_ptr, pcol, dinv, sizes, flag1,
                                                          ue, ie, (unsigned*)Y1);
    k_spmm2<<<(n_full + blk - 1) / blk, blk, 0, stream>>>(row_ptr, pcol, dinv, flag2,
                                                          (const unsigned*)Y1, (unsigned*)X2);
    k_spmm3<<<(n_samp + blk - 1) / blk, blk, 0, stream>>>(row_ptr, pcol, dinv, sizes,
                                                          ue, ie,
                                                          (const unsigned*)Y1,
                                                          (const unsigned*)X2,
                                                          users, pos, neg, out);
}